// Round 1
// baseline (1200.023 us; speedup 1.0000x reference)
//
#include <hip/hip_runtime.h>

typedef __bf16 bf16_t;
typedef bf16_t bf16x8 __attribute__((ext_vector_type(8)));
typedef bf16_t bf16x4 __attribute__((ext_vector_type(4)));
typedef float f32x4 __attribute__((ext_vector_type(4)));

#define DEVI static __device__ __forceinline__

constexpr int BB = 64;
constexpr int NN = 4096;
constexpr int DD = 256;
constexpr int KS = 11;     // real slots
constexpr int KP = 16;     // padded slots (MFMA tile)
constexpr int HH = 512;
constexpr float EPS_A = 1e-8f;
constexpr float LNEPS = 1e-5f;
constexpr float SCALE = 0.0625f;   // 256^-0.5
constexpr int MR = BB * KP;        // 1024 padded slot rows

DEVI float wredf(float v) {
#pragma unroll
  for (int o = 32; o > 0; o >>= 1) v += __shfl_xor(v, o, 64);
  return v;
}

DEVI float sigm(float x) { return 1.f / (1.f + __expf(-x)); }

// ---------------- prep: fp32 -> bf16 weights ----------------
__global__ void prep_weights_k(
    const float* __restrict__ s0, const float* __restrict__ s1, const float* __restrict__ s2,
    const float* __restrict__ s3, const float* __restrict__ s4, const float* __restrict__ s5,
    const float* __restrict__ s6,
    bf16_t* d0, bf16_t* d1, bf16_t* d2, bf16_t* d3, bf16_t* d4, bf16_t* d5, bf16_t* d6) {
  int i = blockIdx.x * 256 + threadIdx.x;
  const float* s; bf16_t* d; int o;
  if      (i < 65536)  { s = s0; d = d0; o = i; }
  else if (i < 131072) { s = s1; d = d1; o = i - 65536; }
  else if (i < 196608) { s = s2; d = d2; o = i - 131072; }
  else if (i < 393216) { s = s3; d = d3; o = i - 196608; }
  else if (i < 589824) { s = s4; d = d4; o = i - 393216; }
  else if (i < 720896) { s = s5; d = d5; o = i - 589824; }
  else                 { s = s6; d = d6; o = i - 720896; }
  d[o] = (bf16_t)s[o];
}

// ---------------- prep: pad slots_init (B,11,D) -> (B,16,D) ----------------
__global__ void init_slots_k(const float* __restrict__ si, float* __restrict__ slots) {
  int i = blockIdx.x * 256 + threadIdx.x;   // over MR*DD
  int d = i & 255, row = i >> 8, b = row >> 4, k = row & 15;
  slots[i] = (k < KS) ? si[((long)b * KS + k) * DD + d] : 0.f;
}

// ---------------- LN(inputs) -> x_bf (one wave per row) ----------------
__global__ void ln_inputs_k(const float* __restrict__ x, const float* __restrict__ w,
                            const float* __restrict__ bsk, bf16_t* __restrict__ o) {
  const int wvi = threadIdx.x >> 6, lane = threadIdx.x & 63;
  const long row = (long)blockIdx.x * 4 + wvi;
  const float4 v = ((const float4*)(x + row * DD))[lane];
  float s = v.x + v.y + v.z + v.w;
  float s2 = v.x * v.x + v.y * v.y + v.z * v.z + v.w * v.w;
  s = wredf(s); s2 = wredf(s2);
  const float mean = s * (1.f / DD);
  const float var = s2 * (1.f / DD) - mean * mean;
  const float rstd = rsqrtf(var + LNEPS);
  const float4 w4 = ((const float4*)w)[lane];
  const float4 b4 = ((const float4*)bsk)[lane];
  bf16x4 ov;
  ov[0] = (bf16_t)((v.x - mean) * rstd * w4.x + b4.x);
  ov[1] = (bf16_t)((v.y - mean) * rstd * w4.y + b4.y);
  ov[2] = (bf16_t)((v.z - mean) * rstd * w4.z + b4.z);
  ov[3] = (bf16_t)((v.w - mean) * rstd * w4.w + b4.w);
  ((bf16x4*)(o + row * DD))[lane] = ov;
}

// ---------------- big GEMM: k = x @ Wk^T  /  vT = (x @ Wv^T)^T ----------------
// MODE 0: A=Wk (m=d, 128 rows at blockIdx.y), B=x (n=row, 256 at blockIdx.x) -> k (row, d) coalesced
// MODE 1: A=x  (m=row, 128 at blockIdx.x),  B=Wv (n=d, all 256)             -> vT (d, row) coalesced
template <int MODE>
__global__ __launch_bounds__(256) void gemm_big_k(const bf16_t* __restrict__ X,
                                                  const bf16_t* __restrict__ W,
                                                  bf16_t* __restrict__ out) {
  __shared__ bf16_t As[128 * 72];   // stride 72 shorts = 144B: 16B-aligned, bank-spread
  __shared__ bf16_t Bs[256 * 72];
  const bf16_t* Ap; const bf16_t* Bp;
  if (MODE == 0) { Ap = W + (long)blockIdx.y * 128 * DD; Bp = X + (long)blockIdx.x * 256 * DD; }
  else           { Ap = X + (long)blockIdx.x * 128 * DD; Bp = W; }
  const int tid = threadIdx.x;
  const int wvi = tid >> 6, lane = tid & 63;
  const int c = lane & 15, q = lane >> 4;
  const int mh = wvi >> 1, nh = wvi & 1;   // wave tile: 64 m x 128 n
  f32x4 acc[4][8];
#pragma unroll
  for (int a = 0; a < 4; a++)
#pragma unroll
    for (int b = 0; b < 8; b++) acc[a][b] = (f32x4){0.f, 0.f, 0.f, 0.f};
  for (int kb = 0; kb < DD; kb += 64) {
#pragma unroll
    for (int it = 0; it < 4; ++it) {
      int id = it * 256 + tid, r = id >> 3, ch = id & 7;
      *(bf16x8*)(As + r * 72 + ch * 8) = *(const bf16x8*)(Ap + (long)r * DD + kb + ch * 8);
    }
#pragma unroll
    for (int it = 0; it < 8; ++it) {
      int id = it * 256 + tid, r = id >> 3, ch = id & 7;
      *(bf16x8*)(Bs + r * 72 + ch * 8) = *(const bf16x8*)(Bp + (long)r * DD + kb + ch * 8);
    }
    __syncthreads();
#pragma unroll
    for (int ks = 0; ks < 2; ++ks) {
      bf16x8 af[4], bfr[8];
#pragma unroll
      for (int mt = 0; mt < 4; mt++)
        af[mt] = *(const bf16x8*)(As + (mh * 64 + mt * 16 + c) * 72 + ks * 32 + q * 8);
#pragma unroll
      for (int nt = 0; nt < 8; nt++)
        bfr[nt] = *(const bf16x8*)(Bs + (nh * 128 + nt * 16 + c) * 72 + ks * 32 + q * 8);
#pragma unroll
      for (int mt = 0; mt < 4; mt++)
#pragma unroll
        for (int nt = 0; nt < 8; nt++)
          acc[mt][nt] = __builtin_amdgcn_mfma_f32_16x16x32_bf16(af[mt], bfr[nt], acc[mt][nt], 0, 0, 0);
    }
    __syncthreads();
  }
#pragma unroll
  for (int mt = 0; mt < 4; mt++) {
#pragma unroll
    for (int nt = 0; nt < 8; nt++) {
      bf16x4 o;
#pragma unroll
      for (int r = 0; r < 4; r++) o[r] = (bf16_t)acc[mt][nt][r];
      if (MODE == 0) {
        int dg = blockIdx.y * 128 + mh * 64 + mt * 16 + q * 4;
        long ng = (long)blockIdx.x * 256 + nh * 128 + nt * 16 + c;
        *(bf16x4*)(out + ng * DD + dg) = o;                   // k[row][d], 4 consecutive d
      } else {
        long ng = (long)blockIdx.x * 128 + mh * 64 + mt * 16 + q * 4;
        int d = nh * 128 + nt * 16 + c;
        long b = ng >> 12; int nin = (int)(ng & 4095);
        *(bf16x4*)(out + (b * DD + d) * NN + nin) = o;        // vT[b][d][n], 4 consecutive n
      }
    }
  }
}

// ---------------- per-iter: LN(slots)->sln_bf, slots->spl_bf, zero scratch ----------------
__global__ void ln_slots_k(const float* __restrict__ slots, const float* __restrict__ lw,
                           const float* __restrict__ lb, bf16_t* __restrict__ sln,
                           bf16_t* __restrict__ spl, float* __restrict__ upd_raw,
                           float* __restrict__ rowsum) {
  const int row = blockIdx.x, d = threadIdx.x;
  upd_raw[row * DD + d] = 0.f;                 // fused zeroing (re-poisoned each launch)
  if (row < 4) rowsum[row * 256 + d] = 0.f;    // MR = 1024 entries
  const int kk = row & 15;
  const int idx = row * DD + d;
  if (kk >= KS) { sln[idx] = (bf16_t)0.f; spl[idx] = (bf16_t)0.f; return; }
  float v = slots[idx];
  spl[idx] = (bf16_t)v;
  __shared__ float r1[4], r2[4];
  float s = wredf(v), s2 = wredf(v * v);
  const int wvi = threadIdx.x >> 6, lane = threadIdx.x & 63;
  if (lane == 0) { r1[wvi] = s; r2[wvi] = s2; }
  __syncthreads();
  float mean = (r1[0] + r1[1] + r1[2] + r1[3]) * (1.f / DD);
  float var = (r2[0] + r2[1] + r2[2] + r2[3]) * (1.f / DD) - mean * mean;
  float rstd = rsqrtf(var + LNEPS);
  sln[idx] = (bf16_t)((v - mean) * rstd * lw[d] + lb[d]);
}

// ---------------- generic small GEMM: out = act(A @ W^T + bias) (+res) ----------------
// per-wave 16x16 tile, M = MR(1024) padded rows, A (M,Kd) bf16 row-major, W (C,Kd) bf16
template <bool BIASF, bool RELUF, bool RESF, int OUTM>   // OUTM: 0=f32, 1=bf16, 2=f32 to (B,11,C)
__global__ void small_gemm_k(const bf16_t* __restrict__ A, const bf16_t* __restrict__ W,
                             const float* __restrict__ bias, const float* __restrict__ res,
                             void* __restrict__ out, int C, int Kd) {
  const int lane = threadIdx.x & 63, c = lane & 15, q = lane >> 4;
  const int wid = blockIdx.x * 4 + (threadIdx.x >> 6);
  const int nct = C >> 4;
  const int mt = wid / nct, ct = wid % nct;
  const bf16_t* ap = A + (long)(mt * 16 + c) * Kd + q * 8;
  const bf16_t* wp = W + (long)(ct * 16 + c) * Kd + q * 8;
  f32x4 acc = (f32x4){0.f, 0.f, 0.f, 0.f};
  for (int k0 = 0; k0 < Kd; k0 += 32)
    acc = __builtin_amdgcn_mfma_f32_16x16x32_bf16(*(const bf16x8*)(ap + k0),
                                                  *(const bf16x8*)(wp + k0), acc, 0, 0, 0);
  const int col = ct * 16 + c;
  const float bv = BIASF ? bias[col] : 0.f;
#pragma unroll
  for (int r = 0; r < 4; r++) {
    const int row = mt * 16 + q * 4 + r;
    float v = acc[r] + bv;
    if (RELUF) v = fmaxf(v, 0.f);
    if (RESF) v += res[(long)row * C + col];
    if (OUTM == 0) ((float*)out)[(long)row * C + col] = v;
    else if (OUTM == 1) ((bf16_t*)out)[(long)row * C + col] = (bf16_t)v;
    else {
      int b = row >> 4, k2 = row & 15;
      if (k2 < KS) ((float*)out)[((long)b * KS + k2) * C + col] = v;
    }
  }
}

// ---------------- dots = SCALE * q @ k^T  (per batch, A=q in regs) ----------------
__global__ void dots_k(const bf16_t* __restrict__ qb, const bf16_t* __restrict__ kb,
                       float* __restrict__ dots) {
  const int b = blockIdx.x >> 3, strip = blockIdx.x & 7;
  const int wvi = threadIdx.x >> 6, lane = threadIdx.x & 63, c = lane & 15, q = lane >> 4;
  const int n0 = strip * 512 + wvi * 128;
  const bf16_t* qp = qb + (long)b * KP * DD;
  bf16x8 af[8];
#pragma unroll
  for (int kc = 0; kc < 8; kc++) af[kc] = *(const bf16x8*)(qp + c * DD + kc * 32 + q * 8);
  const bf16_t* kp = kb + (long)b * NN * DD;
  float* dp0 = dots + (long)b * KP * NN;
#pragma unroll
  for (int nt = 0; nt < 8; nt++) {
    f32x4 acc = (f32x4){0.f, 0.f, 0.f, 0.f};
    const bf16_t* bp = kp + (long)(n0 + nt * 16 + c) * DD + q * 8;
#pragma unroll
    for (int kc = 0; kc < 8; kc++)
      acc = __builtin_amdgcn_mfma_f32_16x16x32_bf16(af[kc], *(const bf16x8*)(bp + kc * 32), acc, 0, 0, 0);
    const int n = n0 + nt * 16 + c;
#pragma unroll
    for (int r = 0; r < 4; r++) dp0[(q * 4 + r) * NN + n] = acc[r] * SCALE;
  }
}

// ---------------- softmax over K (axis=1) + EPS, write bf16 attn, rowsum over N ----------------
__global__ void softmax_k(const float* __restrict__ dots, bf16_t* __restrict__ att,
                          float* __restrict__ rowsum) {
  const int b = blockIdx.x >> 4, nc = blockIdx.x & 15;
  const int n = nc * 256 + threadIdx.x;
  const float* dp = dots + (long)b * KP * NN + n;
  float v[KS];
  float mx = -1e30f;
#pragma unroll
  for (int i = 0; i < KS; i++) { v[i] = dp[i * NN]; mx = fmaxf(mx, v[i]); }
  float sum = 0.f;
#pragma unroll
  for (int i = 0; i < KS; i++) { v[i] = __expf(v[i] - mx); sum += v[i]; }
  const float inv = 1.f / sum;
  bf16_t* ap = att + (long)b * KP * NN + n;
#pragma unroll
  for (int i = 0; i < KS; i++) { v[i] = v[i] * inv + EPS_A; ap[i * NN] = (bf16_t)v[i]; }
#pragma unroll
  for (int i = KS; i < KP; i++) ap[i * NN] = (bf16_t)0.f;   // pad rows -> exact zero
  __shared__ float red[KS][4];
  const int wvi = threadIdx.x >> 6, lane = threadIdx.x & 63;
#pragma unroll
  for (int i = 0; i < KS; i++) {
    float s = wredf(v[i]);
    if (lane == 0) red[i][wvi] = s;
  }
  __syncthreads();
  if (threadIdx.x < KS) {
    float s = red[threadIdx.x][0] + red[threadIdx.x][1] + red[threadIdx.x][2] + red[threadIdx.x][3];
    atomicAdd(&rowsum[b * KP + threadIdx.x], s);
  }
}

// ---------------- updates_raw += attn @ v   (K-split over N, atomic f32) ----------------
__global__ void updates_k(const bf16_t* __restrict__ att, const bf16_t* __restrict__ vT,
                          float* __restrict__ upd) {
  const int b = blockIdx.x >> 3, ksp = blockIdx.x & 7;
  const int wvi = threadIdx.x >> 6, lane = threadIdx.x & 63, c = lane & 15, q = lane >> 4;
  const int d0 = wvi * 64;
  const bf16_t* ab = att + (long)b * KP * NN;
  const bf16_t* vb = vT + (long)b * DD * NN;
  f32x4 acc[4];
#pragma unroll
  for (int dt = 0; dt < 4; dt++) acc[dt] = (f32x4){0.f, 0.f, 0.f, 0.f};
  const int j0b = ksp * 512;
  for (int j0 = j0b; j0 < j0b + 512; j0 += 32) {
    bf16x8 a = *(const bf16x8*)(ab + c * NN + j0 + q * 8);
#pragma unroll
    for (int dt = 0; dt < 4; dt++) {
      bf16x8 bb = *(const bf16x8*)(vb + (long)(d0 + dt * 16 + c) * NN + j0 + q * 8);
      acc[dt] = __builtin_amdgcn_mfma_f32_16x16x32_bf16(a, bb, acc[dt], 0, 0, 0);
    }
  }
  float* ub = upd + (long)b * KP * DD;
#pragma unroll
  for (int dt = 0; dt < 4; dt++)
#pragma unroll
    for (int r = 0; r < 4; r++)
      atomicAdd(&ub[(q * 4 + r) * DD + d0 + dt * 16 + c], acc[dt][r]);
}

// ---------------- upd_bf = bf16(updates_raw / rowsum), pads -> 0 ----------------
__global__ void finalize_k(const float* __restrict__ upd, const float* __restrict__ rowsum,
                           bf16_t* __restrict__ o) {
  const int i = blockIdx.x * 256 + threadIdx.x;
  const int row = i >> 8, kk = row & 15;
  float v = 0.f;
  if (kk < KS) v = upd[i] / rowsum[row];
  o[i] = (bf16_t)v;
}

// ---------------- fused GRU pointwise + LN(slots_new) -> p_bf ----------------
__global__ void gru_ln_k(const float* __restrict__ gi, const float* __restrict__ gh,
                         const float* __restrict__ sin_, const float* __restrict__ lw,
                         const float* __restrict__ lb, float* __restrict__ sout,
                         bf16_t* __restrict__ pbf) {
  const int row = blockIdx.x, d = threadIdx.x;
  const int kk = row & 15;
  const int idx = row * DD + d;
  if (kk >= KS) { sout[idx] = 0.f; pbf[idx] = (bf16_t)0.f; return; }
  const long g = (long)row * 768;
  float r = sigm(gi[g + d] + gh[g + d]);
  float z = sigm(gi[g + 256 + d] + gh[g + 256 + d]);
  float nn = tanhf(gi[g + 512 + d] + r * gh[g + 512 + d]);
  float sp = sin_[idx];
  float s = (1.f - z) * nn + z * sp;
  sout[idx] = s;    // in-place safe: each thread owns its element
  __shared__ float r1[4], r2[4];
  float su = wredf(s), sq = wredf(s * s);
  const int wvi = threadIdx.x >> 6, lane = threadIdx.x & 63;
  if (lane == 0) { r1[wvi] = su; r2[wvi] = sq; }
  __syncthreads();
  float mean = (r1[0] + r1[1] + r1[2] + r1[3]) * (1.f / DD);
  float var = (r2[0] + r2[1] + r2[2] + r2[3]) * (1.f / DD) - mean * mean;
  float rstd = rsqrtf(var + LNEPS);
  pbf[idx] = (bf16_t)((s - mean) * rstd * lw[d] + lb[d]);
}

extern "C" void kernel_launch(void* const* d_in, const int* in_sizes, int n_in, void* d_out,
                              int out_size, void* d_ws, size_t ws_size, hipStream_t stream) {
  (void)in_sizes; (void)n_in; (void)out_size; (void)ws_size;
  const float* inputs = (const float*)d_in[0];
  const float* slots_in = (const float*)d_in[1];
  const float* ln_f_w = (const float*)d_in[2];
  const float* ln_f_b = (const float*)d_in[3];
  const float* ln_s_w = (const float*)d_in[4];
  const float* ln_s_b = (const float*)d_in[5];
  const float* ln_p_w = (const float*)d_in[6];
  const float* ln_p_b = (const float*)d_in[7];
  const float* Wq = (const float*)d_in[8];
  const float* Wk = (const float*)d_in[9];
  const float* Wv = (const float*)d_in[10];
  const float* W_ih = (const float*)d_in[11];
  const float* b_ih = (const float*)d_in[12];
  const float* W_hh = (const float*)d_in[13];
  const float* b_hh = (const float*)d_in[14];
  const float* W1 = (const float*)d_in[15];
  const float* b1 = (const float*)d_in[16];
  const float* W2 = (const float*)d_in[17];
  const float* b2 = (const float*)d_in[18];

  char* p = (char*)d_ws;
  auto alloc = [&](size_t bytes) { char* r = p; p += (bytes + 255) & ~(size_t)255; return r; };
  bf16_t* x_bf  = (bf16_t*)alloc((size_t)BB * NN * DD * 2);
  bf16_t* k_bf  = (bf16_t*)alloc((size_t)BB * NN * DD * 2);
  bf16_t* vT_bf = (bf16_t*)alloc((size_t)BB * NN * DD * 2);
  bf16_t* Wq_bf = (bf16_t*)alloc(65536 * 2);
  bf16_t* Wk_bf = (bf16_t*)alloc(65536 * 2);
  bf16_t* Wv_bf = (bf16_t*)alloc(65536 * 2);
  bf16_t* Wih_bf = (bf16_t*)alloc(196608 * 2);
  bf16_t* Whh_bf = (bf16_t*)alloc(196608 * 2);
  bf16_t* W1_bf = (bf16_t*)alloc(131072 * 2);
  bf16_t* W2_bf = (bf16_t*)alloc(131072 * 2);
  float* slots = (float*)alloc((size_t)MR * DD * 4);
  bf16_t* sln = (bf16_t*)alloc((size_t)MR * DD * 2);
  bf16_t* spl = (bf16_t*)alloc((size_t)MR * DD * 2);
  bf16_t* q_bf = (bf16_t*)alloc((size_t)MR * DD * 2);
  float* dots = (float*)alloc((size_t)BB * KP * NN * 4);
  bf16_t* att = (bf16_t*)alloc((size_t)BB * KP * NN * 2);
  float* rowsum = (float*)alloc((size_t)MR * 4);
  float* upd_raw = (float*)alloc((size_t)MR * DD * 4);
  bf16_t* upd_bf = (bf16_t*)alloc((size_t)MR * DD * 2);
  float* gi = (float*)alloc((size_t)MR * 768 * 4);
  float* gh = (float*)alloc((size_t)MR * 768 * 4);
  bf16_t* pbf = (bf16_t*)alloc((size_t)MR * DD * 2);
  bf16_t* h1 = (bf16_t*)alloc((size_t)MR * HH * 2);

  prep_weights_k<<<3328, 256, 0, stream>>>(Wq, Wk, Wv, W_ih, W_hh, W1, W2, Wq_bf, Wk_bf, Wv_bf,
                                           Wih_bf, Whh_bf, W1_bf, W2_bf);
  init_slots_k<<<1024, 256, 0, stream>>>(slots_in, slots);
  ln_inputs_k<<<65536, 256, 0, stream>>>(inputs, ln_f_w, ln_f_b, x_bf);
  gemm_big_k<0><<<dim3(1024, 2), 256, 0, stream>>>(x_bf, Wk_bf, k_bf);
  gemm_big_k<1><<<dim3(2048, 1), 256, 0, stream>>>(x_bf, Wv_bf, vT_bf);

  for (int t = 0; t < 5; t++) {
    ln_slots_k<<<1024, 256, 0, stream>>>(slots, ln_s_w, ln_s_b, sln, spl, upd_raw, rowsum);
    small_gemm_k<false, false, false, 1><<<256, 256, 0, stream>>>(sln, Wq_bf, nullptr, nullptr, q_bf, 256, 256);
    dots_k<<<512, 256, 0, stream>>>(q_bf, k_bf, dots);
    softmax_k<<<1024, 256, 0, stream>>>(dots, att, rowsum);
    updates_k<<<512, 256, 0, stream>>>(att, vT_bf, upd_raw);
    finalize_k<<<1024, 256, 0, stream>>>(upd_raw, rowsum, upd_bf);
    small_gemm_k<true, false, false, 0><<<768, 256, 0, stream>>>(upd_bf, Wih_bf, b_ih, nullptr, gi, 768, 256);
    small_gemm_k<true, false, false, 0><<<768, 256, 0, stream>>>(spl, Whh_bf, b_hh, nullptr, gh, 768, 256);
    gru_ln_k<<<1024, 256, 0, stream>>>(gi, gh, slots, ln_p_w, ln_p_b, slots, pbf);
    small_gemm_k<true, true, false, 1><<<512, 256, 0, stream>>>(pbf, W1_bf, b1, nullptr, h1, 512, 256);
    if (t < 4)
      small_gemm_k<true, false, true, 0><<<256, 256, 0, stream>>>(h1, W2_bf, b2, slots, slots, 256, 512);
    else
      small_gemm_k<true, false, true, 2><<<256, 256, 0, stream>>>(h1, W2_bf, b2, slots, d_out, 256, 512);
  }
}